// Round 7
// baseline (1570.037 us; speedup 1.0000x reference)
//
#include <hip/hip_runtime.h>
#include <hip/hip_bf16.h>
#include <hip/hip_fp16.h>
#include <math.h>

// GNN: 3-layer GCN + BN + GELU + residual + meanpool + MLP -> scalar.
// R7: wave-per-node aggregation. One node per 64-lane wave; 16B/lane fp16
// gathers cover 4 edges/instr (D=128) or 8 edges/instr (D=64) of the SAME
// node -> wave-uniform start/cnt (zero divergence), coalesced csr index
// loads, 2x unroll = 8-16 edges in flight. shfl_xor folds edge slots at end.

__device__ __forceinline__ float gelu_f(float x) {
    return 0.5f * x * (1.0f + erff(x * 0.7071067811865476f));
}

__device__ __forceinline__ int wave_incl_scan(int v, int lane) {
#pragma unroll
    for (int off = 1; off < 64; off <<= 1) {
        int t = __shfl_up(v, (unsigned)off, 64);
        if (lane >= off) v += t;
    }
    return v;
}

__device__ __forceinline__ void acc8h(const uint4& u, float* f) {
    const __half2* h2p = (const __half2*)&u;
#pragma unroll
    for (int i = 0; i < 4; i++) {
        float2 t = __half22float2(h2p[i]);
        f[2 * i] += t.x;
        f[2 * i + 1] += t.y;
    }
}

// ---- init: deg = 1.0 (self loop), zero double accumulators ----
__global__ void init_kernel(float* __restrict__ deg, double* __restrict__ dbls,
                            int n, int ndbl) {
    int i = blockIdx.x * 256 + threadIdx.x;
    if (i < n) deg[i] = 1.0f;
    if (i < ndbl) dbls[i] = 0.0;
}

__global__ void degree_kernel(const int* __restrict__ col, float* __restrict__ deg, int E) {
    int e = blockIdx.x * 256 + threadIdx.x;
    if (e < E) atomicAdd(&deg[col[e]], 1.0f);
}

__global__ __launch_bounds__(256) void scan1_kernel(const float* __restrict__ deg,
                                                    float* __restrict__ dinv,
                                                    int* __restrict__ offs,
                                                    int* __restrict__ bsums, int n) {
    int i = blockIdx.x * 256 + threadIdx.x;
    int lane = threadIdx.x & 63;
    int wid = threadIdx.x >> 6;
    int cnt = 0;
    if (i < n) {
        float d = deg[i];
        dinv[i] = 1.0f / sqrtf(d);
        cnt = (int)d - 1;
    }
    int incl = wave_incl_scan(cnt, lane);
    __shared__ int ws[4];
    if (lane == 63) ws[wid] = incl;
    __syncthreads();
    if (threadIdx.x == 0) {
        int a = 0;
#pragma unroll
        for (int j = 0; j < 4; j++) { int t = ws[j]; ws[j] = a; a += t; }
        bsums[blockIdx.x] = a;
    }
    __syncthreads();
    int excl = incl - cnt + ws[wid];
    if (i < n) offs[i] = excl;
}

__global__ __launch_bounds__(512) void scan2_kernel(int* __restrict__ bsums, int nblk) {
    int lane = threadIdx.x & 63;
    int wid = threadIdx.x >> 6;
    int v = (threadIdx.x < nblk) ? bsums[threadIdx.x] : 0;
    int incl = wave_incl_scan(v, lane);
    __shared__ int ws[8];
    if (lane == 63) ws[wid] = incl;
    __syncthreads();
    if (threadIdx.x == 0) {
        int a = 0;
#pragma unroll
        for (int j = 0; j < 8; j++) { int t = ws[j]; ws[j] = a; a += t; }
    }
    __syncthreads();
    int excl = incl - v + ws[wid];
    if (threadIdx.x < nblk) bsums[threadIdx.x] = excl;
}

__global__ void scan3_kernel(int* __restrict__ offs, const int* __restrict__ bsums,
                             int* __restrict__ cursor, int n) {
    int i = blockIdx.x * 256 + threadIdx.x;
    if (i < n) {
        int o = offs[i] + bsums[i >> 8];
        offs[i] = o;
        cursor[i] = o;
    }
}

__global__ void fill_kernel(const int* __restrict__ row, const int* __restrict__ col,
                            int* __restrict__ cursor, int* __restrict__ csr, int E) {
    int e = blockIdx.x * 256 + threadIdx.x;
    if (e < E) {
        int c = col[e];
        int pos = atomicAdd(&cursor[c], 1);
        csr[pos] = row[e];
    }
}

// ---- convert x[N][64] fp32 -> xh[N][64] fp16, scaled by dinv[node] ----
__global__ __launch_bounds__(256) void halfconv_kernel(const float* __restrict__ x,
                                                       const float* __restrict__ dinv,
                                                       __half* __restrict__ xh, int N) {
    int t = blockIdx.x * 256 + threadIdx.x;   // one 8-float chunk per thread
    if (t >= N * 8) return;
    int node = t >> 3;
    float dv = dinv[node];
    const float4* p = (const float4*)(x + (size_t)t * 8);
    float4 a = p[0], b = p[1];
    __half2 h[4];
    h[0] = __floats2half2_rn(a.x * dv, a.y * dv);
    h[1] = __floats2half2_rn(a.z * dv, a.w * dv);
    h[2] = __floats2half2_rn(b.x * dv, b.y * dv);
    h[3] = __floats2half2_rn(b.z * dv, b.w * dv);
    *(uint4*)(xh + (size_t)t * 8) = *(uint4*)h;
}

// ---- wave-per-node aggregation ----
// H[i][D] = dinv_i*(Ut[i] + sum in-edge Ut[src]) (+bias); Ut fp16 pre-scaled.
// LPE = D/8 lanes cover one 256B/128B row; EPW = 64/LPE edges per instruction.
template <int D, bool STATS, bool BIAS>
__global__ __launch_bounds__(256) void agg_kernel(const __half* __restrict__ Ut,
                                                  const int* __restrict__ csr,
                                                  const int* __restrict__ offs,
                                                  const float* __restrict__ deg,
                                                  const float* __restrict__ dinv,
                                                  const float* __restrict__ bias,
                                                  float* __restrict__ H,
                                                  double* __restrict__ stats, int n) {
    constexpr int LPE = D / 8;      // lanes per edge row: 16 (D=128) / 8 (D=64)
    constexpr int EPW = 64 / LPE;   // edges per wave instr: 4 / 8
    int wid = threadIdx.x >> 6;     // wave in block (4 waves = 4 nodes)
    int lane = threadIdx.x & 63;
    int node = blockIdx.x * 4 + wid;
    bool act = node < n;

    int q = lane / LPE;             // edge slot
    int cl = lane % LPE;            // 16B chunk within row

    float a[8], b[8];
#pragma unroll
    for (int c = 0; c < 8; c++) { a[c] = 0.f; b[c] = 0.f; }

    int start = 0, cnt = 0;
    float dvi = 0.f;
    if (act) {
        start = offs[node];
        cnt = (int)deg[node] - 1;
        dvi = dinv[node];
        if (q == 0) {   // self loop handled by slot 0
            uint4 u = *(const uint4*)(Ut + (size_t)node * D + cl * 8);
            acc8h(u, a);
        }
    }
    const __half* __restrict__ base = Ut + cl * 8;
    int j = 0;
    if (act) {
        for (; j + 2 * EPW <= cnt; j += 2 * EPW) {
            int s0 = csr[start + j + q];
            int s1 = csr[start + j + EPW + q];
            uint4 u0 = *(const uint4*)(base + (size_t)s0 * D);
            uint4 u1 = *(const uint4*)(base + (size_t)s1 * D);
            acc8h(u0, a);
            acc8h(u1, b);
        }
        if (j + EPW <= cnt) {
            int s0 = csr[start + j + q];
            uint4 u0 = *(const uint4*)(base + (size_t)s0 * D);
            acc8h(u0, a);
            j += EPW;
        }
        int r = j + q;
        if (r < cnt) {   // tail: partial slot mask
            int s0 = csr[start + r];
            uint4 u0 = *(const uint4*)(base + (size_t)s0 * D);
            acc8h(u0, b);
        }
    }

#pragma unroll
    for (int c = 0; c < 8; c++) a[c] += b[c];
    // fold edge slots: lanes differing by multiples of LPE hold same channels
#pragma unroll
    for (int m = LPE; m < 64; m <<= 1) {
#pragma unroll
        for (int c = 0; c < 8; c++) a[c] += __shfl_xor(a[c], m, 64);
    }

    float h[8];
#pragma unroll
    for (int c = 0; c < 8; c++) {
        float v = a[c] * dvi;
        if (BIAS) v += bias[cl * 8 + c];
        h[c] = act ? v : 0.f;
    }
    if (act && q == 0) {
        float* dst = H + (size_t)node * D + cl * 8;
        *(float4*)dst = make_float4(h[0], h[1], h[2], h[3]);
        *(float4*)(dst + 4) = make_float4(h[4], h[5], h[6], h[7]);
    }

    if (STATS) {
        __shared__ float ps[4][LPE][8], pq[4][LPE][8];
        if (lane < LPE) {
#pragma unroll
            for (int c = 0; c < 8; c++) {
                ps[wid][lane][c] = h[c];
                pq[wid][lane][c] = h[c] * h[c];
            }
        }
        __syncthreads();
        if (threadIdx.x < D) {
            int cgi = threadIdx.x >> 3, ci = threadIdx.x & 7;
            float t1 = ps[0][cgi][ci] + ps[1][cgi][ci] + ps[2][cgi][ci] + ps[3][cgi][ci];
            float t2 = pq[0][cgi][ci] + pq[1][cgi][ci] + pq[2][cgi][ci] + pq[3][cgi][ci];
            atomicAdd(&stats[threadIdx.x], (double)t1);
            atomicAdd(&stats[D + threadIdx.x], (double)t2);
        }
    }
}

// ---- register-blocked GEMM ----
template <int DIN, int DOUT, bool BNIN, bool BIAS, bool DINVOUT, bool HALFOUT, bool STATS>
__global__ __launch_bounds__(256) void gemm_kernel(const float* __restrict__ Hin,
                                                   const float* __restrict__ W,
                                                   const float* __restrict__ scale,
                                                   const float* __restrict__ shift,
                                                   const float* __restrict__ bias,
                                                   const float* __restrict__ dinv,
                                                   float* __restrict__ Out,
                                                   double* __restrict__ stats, int n) {
    constexpr int BNODES = 64;
    constexpr int KT = 32;
    constexpr int HP = DIN + 4;
    constexpr int VC = DOUT / 16;      // 8 (DOUT=128) or 4 (DOUT=64)
    constexpr int C4 = VC / 4;
    __shared__ float Hs[BNODES * HP];
    __shared__ float Ws[KT * DOUT];
    __shared__ float ps[STATS ? 4 : 1][16][VC];
    __shared__ float pq[STATS ? 4 : 1][16][VC];

    int node0 = blockIdx.x * BNODES;
    int nv = n - node0;
    if (nv > BNODES) nv = BNODES;
    int cg = threadIdx.x & 15;
    int ng = threadIdx.x >> 4;

    constexpr int F4 = BNODES * (DIN / 4);
    for (int f = threadIdx.x; f < F4; f += 256) {
        int nn = f / (DIN / 4);
        int k4 = f - nn * (DIN / 4);
        float4 v = make_float4(0.f, 0.f, 0.f, 0.f);
        if (nn < nv)
            v = *(const float4*)(Hin + (size_t)(node0 + nn) * DIN + k4 * 4);
        if (BNIN) {
            float4 sc = *(const float4*)(scale + k4 * 4);
            float4 sh = *(const float4*)(shift + k4 * 4);
            v.x = gelu_f(fmaf(v.x, sc.x, sh.x));
            v.y = gelu_f(fmaf(v.y, sc.y, sh.y));
            v.z = gelu_f(fmaf(v.z, sc.z, sh.z));
            v.w = gelu_f(fmaf(v.w, sc.w, sh.w));
        }
        *(float4*)(Hs + nn * HP + k4 * 4) = v;
    }

    float acc[4][VC];
#pragma unroll
    for (int i = 0; i < 4; i++)
#pragma unroll
        for (int c = 0; c < VC; c++) acc[i][c] = 0.0f;

    for (int kb = 0; kb < DIN; kb += KT) {
        __syncthreads();
        for (int f = threadIdx.x; f < KT * DOUT / 4; f += 256)
            *(float4*)(Ws + f * 4) = *(const float4*)(W + (size_t)kb * DOUT + f * 4);
        __syncthreads();
#pragma unroll
        for (int kk = 0; kk < KT; kk++) {
            float h[4];
#pragma unroll
            for (int i = 0; i < 4; i++)
                h[i] = Hs[(ng * 4 + i) * HP + kb + kk];
            float w[VC];
#pragma unroll
            for (int c = 0; c < C4; c++) {
                float4 w4 = *(const float4*)(Ws + kk * DOUT + cg * VC + c * 4);
                w[c * 4 + 0] = w4.x; w[c * 4 + 1] = w4.y;
                w[c * 4 + 2] = w4.z; w[c * 4 + 3] = w4.w;
            }
#pragma unroll
            for (int i = 0; i < 4; i++)
#pragma unroll
                for (int c = 0; c < VC; c++)
                    acc[i][c] = fmaf(h[i], w[c], acc[i][c]);
        }
    }

    float fin[4][VC];
#pragma unroll
    for (int i = 0; i < 4; i++) {
        int nn = ng * 4 + i;
        bool valid = nn < nv;
        int node = node0 + nn;
        float dv = 1.0f;
        if (DINVOUT && valid) dv = dinv[node];
#pragma unroll
        for (int c = 0; c < VC; c++) {
            float f = acc[i][c] * dv;
            if (BIAS) f += bias[cg * VC + c];
            fin[i][c] = valid ? f : 0.f;
        }
        if (valid) {
            if (HALFOUT) {
                __half* hp = (__half*)Out + (size_t)node * DOUT + cg * VC;
                if (VC == 8) {
                    __half2 pk[4];
                    pk[0] = __floats2half2_rn(fin[i][0], fin[i][1]);
                    pk[1] = __floats2half2_rn(fin[i][2], fin[i][3]);
                    pk[2] = __floats2half2_rn(fin[i][4], fin[i][5]);
                    pk[3] = __floats2half2_rn(fin[i][6], fin[i][7]);
                    *(uint4*)hp = *(uint4*)pk;
                } else {
                    __half2 pk[2];
                    pk[0] = __floats2half2_rn(fin[i][0], fin[i][1]);
                    pk[1] = __floats2half2_rn(fin[i][2], fin[i][3]);
                    *(uint2*)hp = *(uint2*)pk;
                }
            } else {
#pragma unroll
                for (int c = 0; c < C4; c++)
                    *(float4*)(Out + (size_t)node * DOUT + cg * VC + c * 4) =
                        make_float4(fin[i][c * 4 + 0], fin[i][c * 4 + 1],
                                    fin[i][c * 4 + 2], fin[i][c * 4 + 3]);
            }
        }
    }

    if (STATS) {
        float s[VC], q[VC];
#pragma unroll
        for (int c = 0; c < VC; c++) {
            s[c] = fin[0][c] + fin[1][c] + fin[2][c] + fin[3][c];
            q[c] = fin[0][c] * fin[0][c] + fin[1][c] * fin[1][c] +
                   fin[2][c] * fin[2][c] + fin[3][c] * fin[3][c];
        }
#pragma unroll
        for (int st = 16; st < 64; st <<= 1) {
#pragma unroll
            for (int c = 0; c < VC; c++) {
                s[c] += __shfl_xor(s[c], st, 64);
                q[c] += __shfl_xor(q[c], st, 64);
            }
        }
        int wid = threadIdx.x >> 6;
        int lane = threadIdx.x & 63;
        if (lane < 16) {
#pragma unroll
            for (int c = 0; c < VC; c++) { ps[wid][lane][c] = s[c]; pq[wid][lane][c] = q[c]; }
        }
        __syncthreads();
        if (threadIdx.x < DOUT) {
            int col = threadIdx.x;
            int cgi = col / VC, ci = col % VC;
            float t = ps[0][cgi][ci] + ps[1][cgi][ci] + ps[2][cgi][ci] + ps[3][cgi][ci];
            float t2 = pq[0][cgi][ci] + pq[1][cgi][ci] + pq[2][cgi][ci] + pq[3][cgi][ci];
            atomicAdd(&stats[col], (double)t);
            atomicAdd(&stats[DOUT + col], (double)t2);
        }
    }
}

// ---- stats sums -> per-channel scale/shift floats ----
template <int D>
__global__ void finalize_kernel(const double* __restrict__ stats,
                                const float* __restrict__ g, const float* __restrict__ be,
                                float* __restrict__ scale, float* __restrict__ shift, int n) {
    int c = threadIdx.x;
    if (c < D) {
        double mu = stats[c] / n;
        double var = stats[c + D] / n - mu * mu;
        double inv = 1.0 / sqrt(var + 1e-5);
        double sc = (double)g[c] * inv;
        scale[c] = (float)sc;
        shift[c] = (float)((double)be[c] - mu * sc);
    }
}

// ---- layer-3: BN normalize + GELU + residual(x) + mean-pool accumulate ----
__global__ __launch_bounds__(256) void norm_pool_kernel(const float* __restrict__ X3,
                                                        const float* __restrict__ x0,
                                                        const double* __restrict__ stats,
                                                        const float* __restrict__ gw,
                                                        const float* __restrict__ be,
                                                        double* __restrict__ pool, int n) {
    constexpr int D = 64;
    constexpr int RPB = 4;
    int c = threadIdx.x % D;
    double mu = stats[c] / n;
    double var = stats[c + D] / n - mu * mu;
    double inv = 1.0 / sqrt(var + 1e-5);
    float scale = (float)((double)gw[c] * inv);
    float shift = (float)((double)be[c] - mu * (double)gw[c] * inv);
    int r0 = threadIdx.x / D;
    int rowsPerGrid = gridDim.x * RPB;
    double s = 0.0;
    for (int r = blockIdx.x * RPB + r0; r < n; r += rowsPerGrid) {
        size_t idx = (size_t)r * D + c;
        float t = fmaf(X3[idx], scale, shift);
        float res = x0[idx] + gelu_f(t);
        s += res;
    }
    __shared__ double sh[256];
    sh[threadIdx.x] = s;
    __syncthreads();
    if (threadIdx.x < D) {
#pragma unroll
        for (int j = 1; j < RPB; j++) s += sh[threadIdx.x + j * D];
        atomicAdd(&pool[c], s);
    }
}

// ---- head MLP: 64 ->128 ->64 ->32 ->1, single block ----
__global__ __launch_bounds__(128) void mlp_kernel(const double* __restrict__ pool,
                                                  const float* __restrict__ w1, const float* __restrict__ b1,
                                                  const float* __restrict__ w2, const float* __restrict__ b2,
                                                  const float* __restrict__ w3, const float* __restrict__ b3,
                                                  const float* __restrict__ w4, const float* __restrict__ b4,
                                                  float* __restrict__ out, int n) {
    __shared__ float v0[64], h1[128], h2[64], h3[32];
    int t = threadIdx.x;
    if (t < 64) v0[t] = (float)(pool[t] / (double)n);
    __syncthreads();
    if (t < 128) {
        float a = b1[t];
        for (int k = 0; k < 64; k++) a = fmaf(v0[k], w1[k * 128 + t], a);
        h1[t] = gelu_f(a);
    }
    __syncthreads();
    if (t < 64) {
        float a = b2[t];
        for (int k = 0; k < 128; k++) a = fmaf(h1[k], w2[k * 64 + t], a);
        h2[t] = gelu_f(a);
    }
    __syncthreads();
    if (t < 32) {
        float a = b3[t];
        for (int k = 0; k < 64; k++) a = fmaf(h2[k], w3[k * 32 + t], a);
        h3[t] = gelu_f(a);
    }
    __syncthreads();
    if (t == 0) {
        float a = b4[0];
        for (int k = 0; k < 32; k++) a = fmaf(h3[k], w4[k], a);
        out[0] = a;
    }
}

extern "C" void kernel_launch(void* const* d_in, const int* in_sizes, int n_in,
                              void* d_out, int out_size, void* d_ws, size_t ws_size,
                              hipStream_t stream) {
    const float* x    = (const float*)d_in[0];
    const int*   ei   = (const int*)d_in[1];
    const float* W1   = (const float*)d_in[2];
    const float* b1   = (const float*)d_in[3];
    const float* g1   = (const float*)d_in[4];
    const float* be1  = (const float*)d_in[5];
    const float* W2   = (const float*)d_in[6];
    const float* b2   = (const float*)d_in[7];
    const float* g2   = (const float*)d_in[8];
    const float* be2  = (const float*)d_in[9];
    const float* W3   = (const float*)d_in[10];
    const float* b3   = (const float*)d_in[11];
    const float* g3   = (const float*)d_in[12];
    const float* be3  = (const float*)d_in[13];
    const float* fc1w = (const float*)d_in[14];
    const float* fc1b = (const float*)d_in[15];
    const float* fc2w = (const float*)d_in[16];
    const float* fc2b = (const float*)d_in[17];
    const float* fc3w = (const float*)d_in[18];
    const float* fc3b = (const float*)d_in[19];
    const float* fc4w = (const float*)d_in[20];
    const float* fc4b = (const float*)d_in[21];

    const int N = in_sizes[0] / 64;
    const int E = in_sizes[1] / 2;
    const int* e_row = ei;       // source
    const int* e_col = ei + E;   // target (aggregation index)

    // ---- workspace layout (~110 MB) ----
    char* ws = (char*)d_ws;
    size_t off = 0;
    double* stats1 = (double*)(ws + off); off += 256 * sizeof(double);
    double* stats2 = (double*)(ws + off); off += 256 * sizeof(double);
    double* stats3 = (double*)(ws + off); off += 256 * sizeof(double);
    double* pool   = (double*)(ws + off); off += 64 * sizeof(double);
    float* scale1 = (float*)(ws + off); off += 128 * sizeof(float);
    float* shift1 = (float*)(ws + off); off += 128 * sizeof(float);
    float* scale2 = (float*)(ws + off); off += 128 * sizeof(float);
    float* shift2 = (float*)(ws + off); off += 128 * sizeof(float);
    float* deg   = (float*)(ws + off); off += (size_t)N * sizeof(float);
    float* dinv  = (float*)(ws + off); off += (size_t)N * sizeof(float);
    off = (off + 15) & ~(size_t)15;
    int* offs    = (int*)(ws + off); off += (size_t)N * sizeof(int);
    int* cursor  = (int*)(ws + off); off += (size_t)N * sizeof(int);
    int* bsums   = (int*)(ws + off); off += 512 * sizeof(int);
    int* csr     = (int*)(ws + off); off += (size_t)E * sizeof(int);
    off = (off + 255) & ~(size_t)255;
    __half* Ut   = (__half*)(ws + off); off += (size_t)N * 128 * sizeof(__half);  // fp16 gather table
    float* A1    = (float*)(ws + off);  off += (size_t)N * 64 * sizeof(float);    // agg1 out (fp32)
    float* H     = (float*)(ws + off);  off += (size_t)N * 128 * sizeof(float);   // fp32 row-major
    __half* xh   = Ut;  // alias: xh dead after agg1, before gemm2 writes Ut

    const int nb256 = (N + 255) / 256;
    const int ebl = (E + 255) / 256;
    const int aggblk = (N + 3) / 4;     // 4 nodes (waves) per agg block

    init_kernel<<<nb256, 256, 0, stream>>>(deg, stats1, N, 832);
    degree_kernel<<<ebl, 256, 0, stream>>>(e_col, deg, E);
    scan1_kernel<<<nb256, 256, 0, stream>>>(deg, dinv, offs, bsums, N);
    scan2_kernel<<<1, 512, 0, stream>>>(bsums, nb256);
    scan3_kernel<<<nb256, 256, 0, stream>>>(offs, bsums, cursor, N);
    fill_kernel<<<ebl, 256, 0, stream>>>(e_row, e_col, cursor, csr, E);

    // Layer 1: x -> fp16 (dinv-scaled); agg 64-dim -> A1; GEMM(+b1,+stats1) -> H1
    halfconv_kernel<<<(N * 8 + 255) / 256, 256, 0, stream>>>(x, dinv, xh, N);
    agg_kernel<64, false, false><<<aggblk, 256, 0, stream>>>(
        xh, csr, offs, deg, dinv, nullptr, A1, nullptr, N);
    gemm_kernel<64, 128, false, true, false, false, true><<<(N + 63) / 64, 256, 0, stream>>>(
        A1, W1, nullptr, nullptr, b1, dinv, H, stats1, N);
    finalize_kernel<128><<<1, 128, 0, stream>>>(stats1, g1, be1, scale1, shift1, N);

    // Layer 2: GEMM (BN1+GELU fused, dinv-scaled, fp16 out) -> Ut; agg(+b2,+stats2) -> H2
    gemm_kernel<128, 128, true, false, true, true, false><<<(N + 63) / 64, 256, 0, stream>>>(
        H, W2, scale1, shift1, nullptr, dinv, (float*)Ut, nullptr, N);
    agg_kernel<128, true, true><<<aggblk, 256, 0, stream>>>(
        Ut, csr, offs, deg, dinv, b2, H, stats2, N);
    finalize_kernel<128><<<1, 128, 0, stream>>>(stats2, g2, be2, scale2, shift2, N);

    // Layer 3: GEMM (BN2+GELU fused, fp16 out 64) -> Ut; agg(+b3,+stats3) -> H3
    gemm_kernel<128, 64, true, false, true, true, false><<<(N + 63) / 64, 256, 0, stream>>>(
        H, W3, scale2, shift2, nullptr, dinv, (float*)Ut, nullptr, N);
    agg_kernel<64, true, true><<<aggblk, 256, 0, stream>>>(
        Ut, csr, offs, deg, dinv, b3, H, stats3, N);

    // Epilogue: BN3+GELU+residual+meanpool, then head MLP
    norm_pool_kernel<<<1024, 256, 0, stream>>>(H, x, stats3, g3, be3, pool, N);
    mlp_kernel<<<1, 128, 0, stream>>>(pool, fc1w, fc1b, fc2w, fc2b, fc3w, fc3b,
                                      fc4w, fc4b, (float*)d_out, N);
}

// Round 8
// 944.612 us; speedup vs baseline: 1.6621x; 1.6621x over previous
//
#include <hip/hip_runtime.h>
#include <hip/hip_bf16.h>
#include <math.h>

// GNN: 3-layer GCN + BN + GELU + residual + meanpool + MLP -> scalar.
// R8: best-of-all-rounds reassembly. Aggregation reverted to R2's EXACT
// measured-best geometry (fp32 table, float4 16B/lane, D/4 lanes/node,
// 2 nodes/wave, x4 unroll dual-acc -> 124us @ 3.65TB/s). fp16 experiments
// (R4-R7) all collapsed fetch-rate; deleted. Kept: BN stats fused into
// agg/gemm epilogues, BN+GELU fused into GEMM staging, dinv prescale.

__device__ __forceinline__ float gelu_f(float x) {
    return 0.5f * x * (1.0f + erff(x * 0.7071067811865476f));
}

__device__ __forceinline__ int wave_incl_scan(int v, int lane) {
#pragma unroll
    for (int off = 1; off < 64; off <<= 1) {
        int t = __shfl_up(v, (unsigned)off, 64);
        if (lane >= off) v += t;
    }
    return v;
}

// ---- init: deg = 1.0 (self loop), zero double accumulators ----
__global__ void init_kernel(float* __restrict__ deg, double* __restrict__ dbls,
                            int n, int ndbl) {
    int i = blockIdx.x * 256 + threadIdx.x;
    if (i < n) deg[i] = 1.0f;
    if (i < ndbl) dbls[i] = 0.0;
}

__global__ void degree_kernel(const int* __restrict__ col, float* __restrict__ deg, int E) {
    int e = blockIdx.x * 256 + threadIdx.x;
    if (e < E) atomicAdd(&deg[col[e]], 1.0f);
}

__global__ __launch_bounds__(256) void scan1_kernel(const float* __restrict__ deg,
                                                    float* __restrict__ dinv,
                                                    int* __restrict__ offs,
                                                    int* __restrict__ bsums, int n) {
    int i = blockIdx.x * 256 + threadIdx.x;
    int lane = threadIdx.x & 63;
    int wid = threadIdx.x >> 6;
    int cnt = 0;
    if (i < n) {
        float d = deg[i];
        dinv[i] = 1.0f / sqrtf(d);
        cnt = (int)d - 1;
    }
    int incl = wave_incl_scan(cnt, lane);
    __shared__ int ws[4];
    if (lane == 63) ws[wid] = incl;
    __syncthreads();
    if (threadIdx.x == 0) {
        int a = 0;
#pragma unroll
        for (int j = 0; j < 4; j++) { int t = ws[j]; ws[j] = a; a += t; }
        bsums[blockIdx.x] = a;
    }
    __syncthreads();
    int excl = incl - cnt + ws[wid];
    if (i < n) offs[i] = excl;
}

__global__ __launch_bounds__(512) void scan2_kernel(int* __restrict__ bsums, int nblk) {
    int lane = threadIdx.x & 63;
    int wid = threadIdx.x >> 6;
    int v = (threadIdx.x < nblk) ? bsums[threadIdx.x] : 0;
    int incl = wave_incl_scan(v, lane);
    __shared__ int ws[8];
    if (lane == 63) ws[wid] = incl;
    __syncthreads();
    if (threadIdx.x == 0) {
        int a = 0;
#pragma unroll
        for (int j = 0; j < 8; j++) { int t = ws[j]; ws[j] = a; a += t; }
    }
    __syncthreads();
    int excl = incl - v + ws[wid];
    if (threadIdx.x < nblk) bsums[threadIdx.x] = excl;
}

__global__ void scan3_kernel(int* __restrict__ offs, const int* __restrict__ bsums,
                             int* __restrict__ cursor, int n) {
    int i = blockIdx.x * 256 + threadIdx.x;
    if (i < n) {
        int o = offs[i] + bsums[i >> 8];
        offs[i] = o;
        cursor[i] = o;
    }
}

__global__ void fill_kernel(const int* __restrict__ row, const int* __restrict__ col,
                            int* __restrict__ cursor, int* __restrict__ csr, int E) {
    int e = blockIdx.x * 256 + threadIdx.x;
    if (e < E) {
        int c = col[e];
        int pos = atomicAdd(&cursor[c], 1);
        csr[pos] = row[e];
    }
}

// ---- aggregation (R2-exact gather loop) + optional fused BN stats ----
// PRE=true : Out[i] = dinv_i * (dinv_i*U_i + sum_j dinv_j*U_j)         (no bias)
// PRE=false: Out[i] = dinv_i * (U_i + sum_j U_j) + bias                (U pre-scaled)
template <int D, bool PRE, bool STATS, bool BIAS>
__global__ __launch_bounds__(256) void agg_kernel(const float* __restrict__ U,
                                                  const int* __restrict__ csr,
                                                  const int* __restrict__ offs,
                                                  const float* __restrict__ deg,
                                                  const float* __restrict__ dinv,
                                                  const float* __restrict__ bias,
                                                  float* __restrict__ Out,
                                                  double* __restrict__ stats, int n) {
    constexpr int GPN = D / 4;          // lanes per node (32 for D=128, 16 for D=64)
    constexpr int NPB = 256 / GPN;
    int g = threadIdx.x / GPN;
    int cl = threadIdx.x % GPN;
    int node = blockIdx.x * NPB + g;
    bool act = node < n;
    int c4 = cl * 4;

    float4 a0 = make_float4(0.f, 0.f, 0.f, 0.f), a1 = a0;
    int start = 0, cnt = 0;
    float dvi = 0.f;
    if (act) {
        start = offs[node];
        cnt = (int)deg[node] - 1;
        dvi = dinv[node];
        float4 self = *(const float4*)(U + (size_t)node * D + c4);
        if (PRE) {
            a0.x = self.x * dvi; a0.y = self.y * dvi;
            a0.z = self.z * dvi; a0.w = self.w * dvi;
        } else {
            a0 = self;
        }
    }
    int j = 0;
    for (; j + 4 <= cnt; j += 4) {
        int s0 = csr[start + j];
        int s1 = csr[start + j + 1];
        int s2 = csr[start + j + 2];
        int s3 = csr[start + j + 3];
        float4 v0 = *(const float4*)(U + (size_t)s0 * D + c4);
        float4 v1 = *(const float4*)(U + (size_t)s1 * D + c4);
        float4 v2 = *(const float4*)(U + (size_t)s2 * D + c4);
        float4 v3 = *(const float4*)(U + (size_t)s3 * D + c4);
        if (PRE) {
            float d0 = dinv[s0], d1 = dinv[s1], d2 = dinv[s2], d3 = dinv[s3];
            v0.x *= d0; v0.y *= d0; v0.z *= d0; v0.w *= d0;
            v1.x *= d1; v1.y *= d1; v1.z *= d1; v1.w *= d1;
            v2.x *= d2; v2.y *= d2; v2.z *= d2; v2.w *= d2;
            v3.x *= d3; v3.y *= d3; v3.z *= d3; v3.w *= d3;
        }
        a0.x += v0.x; a0.y += v0.y; a0.z += v0.z; a0.w += v0.w;
        a1.x += v1.x; a1.y += v1.y; a1.z += v1.z; a1.w += v1.w;
        a0.x += v2.x; a0.y += v2.y; a0.z += v2.z; a0.w += v2.w;
        a1.x += v3.x; a1.y += v3.y; a1.z += v3.z; a1.w += v3.w;
    }
    for (; j < cnt; j++) {
        int s = csr[start + j];
        float4 v = *(const float4*)(U + (size_t)s * D + c4);
        if (PRE) {
            float d = dinv[s];
            v.x *= d; v.y *= d; v.z *= d; v.w *= d;
        }
        a0.x += v.x; a0.y += v.y; a0.z += v.z; a0.w += v.w;
    }
    float4 acc;
    acc.x = a0.x + a1.x; acc.y = a0.y + a1.y;
    acc.z = a0.z + a1.z; acc.w = a0.w + a1.w;

    float h[4];
    h[0] = acc.x * dvi; h[1] = acc.y * dvi;
    h[2] = acc.z * dvi; h[3] = acc.w * dvi;
    if (BIAS) {
        float4 b4 = *(const float4*)(bias + c4);
        h[0] += b4.x; h[1] += b4.y; h[2] += b4.z; h[3] += b4.w;
    }
    if (act) {
        *(float4*)(Out + (size_t)node * D + c4) = make_float4(h[0], h[1], h[2], h[3]);
    } else {
        h[0] = h[1] = h[2] = h[3] = 0.f;   // no stats contribution
    }

    if (STATS) {
        float s[4], q[4];
#pragma unroll
        for (int c = 0; c < 4; c++) { s[c] = h[c]; q[c] = h[c] * h[c]; }
        // fold nodes sharing the wave: lanes differing by multiples of GPN
#pragma unroll
        for (int m = GPN; m < 64; m <<= 1) {
#pragma unroll
            for (int c = 0; c < 4; c++) {
                s[c] += __shfl_xor(s[c], m, 64);
                q[c] += __shfl_xor(q[c], m, 64);
            }
        }
        __shared__ float ps[4][GPN][4], pq[4][GPN][4];
        int wid = threadIdx.x >> 6;
        int lane = threadIdx.x & 63;
        if (lane < GPN) {
#pragma unroll
            for (int c = 0; c < 4; c++) { ps[wid][lane][c] = s[c]; pq[wid][lane][c] = q[c]; }
        }
        __syncthreads();
        if (threadIdx.x < D) {
            int cgi = threadIdx.x >> 2, ci = threadIdx.x & 3;
            float t1 = ps[0][cgi][ci] + ps[1][cgi][ci] + ps[2][cgi][ci] + ps[3][cgi][ci];
            float t2 = pq[0][cgi][ci] + pq[1][cgi][ci] + pq[2][cgi][ci] + pq[3][cgi][ci];
            atomicAdd(&stats[threadIdx.x], (double)t1);
            atomicAdd(&stats[D + threadIdx.x], (double)t2);
        }
    }
}

// ---- register-blocked GEMM ----
// BNIN: scale/shift+GELU on input staging. STATS: fused per-channel sum/sumsq.
template <int DIN, int DOUT, bool BNIN, bool BIAS, bool DINVOUT, bool STATS>
__global__ __launch_bounds__(256) void gemm_kernel(const float* __restrict__ Hin,
                                                   const float* __restrict__ W,
                                                   const float* __restrict__ scale,
                                                   const float* __restrict__ shift,
                                                   const float* __restrict__ bias,
                                                   const float* __restrict__ dinv,
                                                   float* __restrict__ Out,
                                                   double* __restrict__ stats, int n) {
    constexpr int BNODES = 64;
    constexpr int KT = 32;
    constexpr int HP = DIN + 4;
    constexpr int VC = DOUT / 16;      // 8 (DOUT=128) or 4 (DOUT=64)
    constexpr int C4 = VC / 4;
    __shared__ float Hs[BNODES * HP];
    __shared__ float Ws[KT * DOUT];
    __shared__ float ps[STATS ? 4 : 1][16][VC];
    __shared__ float pq[STATS ? 4 : 1][16][VC];

    int node0 = blockIdx.x * BNODES;
    int nv = n - node0;
    if (nv > BNODES) nv = BNODES;
    int cg = threadIdx.x & 15;
    int ng = threadIdx.x >> 4;

    constexpr int F4 = BNODES * (DIN / 4);
    for (int f = threadIdx.x; f < F4; f += 256) {
        int nn = f / (DIN / 4);
        int k4 = f - nn * (DIN / 4);
        float4 v = make_float4(0.f, 0.f, 0.f, 0.f);
        if (nn < nv)
            v = *(const float4*)(Hin + (size_t)(node0 + nn) * DIN + k4 * 4);
        if (BNIN) {
            float4 sc = *(const float4*)(scale + k4 * 4);
            float4 sh = *(const float4*)(shift + k4 * 4);
            v.x = gelu_f(fmaf(v.x, sc.x, sh.x));
            v.y = gelu_f(fmaf(v.y, sc.y, sh.y));
            v.z = gelu_f(fmaf(v.z, sc.z, sh.z));
            v.w = gelu_f(fmaf(v.w, sc.w, sh.w));
        }
        *(float4*)(Hs + nn * HP + k4 * 4) = v;
    }

    float acc[4][VC];
#pragma unroll
    for (int i = 0; i < 4; i++)
#pragma unroll
        for (int c = 0; c < VC; c++) acc[i][c] = 0.0f;

    for (int kb = 0; kb < DIN; kb += KT) {
        __syncthreads();
        for (int f = threadIdx.x; f < KT * DOUT / 4; f += 256)
            *(float4*)(Ws + f * 4) = *(const float4*)(W + (size_t)kb * DOUT + f * 4);
        __syncthreads();
#pragma unroll
        for (int kk = 0; kk < KT; kk++) {
            float h[4];
#pragma unroll
            for (int i = 0; i < 4; i++)
                h[i] = Hs[(ng * 4 + i) * HP + kb + kk];
            float w[VC];
#pragma unroll
            for (int c = 0; c < C4; c++) {
                float4 w4 = *(const float4*)(Ws + kk * DOUT + cg * VC + c * 4);
                w[c * 4 + 0] = w4.x; w[c * 4 + 1] = w4.y;
                w[c * 4 + 2] = w4.z; w[c * 4 + 3] = w4.w;
            }
#pragma unroll
            for (int i = 0; i < 4; i++)
#pragma unroll
                for (int c = 0; c < VC; c++)
                    acc[i][c] = fmaf(h[i], w[c], acc[i][c]);
        }
    }

    float fin[4][VC];
#pragma unroll
    for (int i = 0; i < 4; i++) {
        int nn = ng * 4 + i;
        bool valid = nn < nv;
        int node = node0 + nn;
        float dv = 1.0f;
        if (DINVOUT && valid) dv = dinv[node];
#pragma unroll
        for (int c = 0; c < VC; c++) {
            float f = acc[i][c] * dv;
            if (BIAS) f += bias[cg * VC + c];
            fin[i][c] = valid ? f : 0.f;
        }
        if (valid) {
#pragma unroll
            for (int c = 0; c < C4; c++)
                *(float4*)(Out + (size_t)node * DOUT + cg * VC + c * 4) =
                    make_float4(fin[i][c * 4 + 0], fin[i][c * 4 + 1],
                                fin[i][c * 4 + 2], fin[i][c * 4 + 3]);
        }
    }

    if (STATS) {
        float s[VC], q[VC];
#pragma unroll
        for (int c = 0; c < VC; c++) {
            s[c] = fin[0][c] + fin[1][c] + fin[2][c] + fin[3][c];
            q[c] = fin[0][c] * fin[0][c] + fin[1][c] * fin[1][c] +
                   fin[2][c] * fin[2][c] + fin[3][c] * fin[3][c];
        }
#pragma unroll
        for (int st = 16; st < 64; st <<= 1) {
#pragma unroll
            for (int c = 0; c < VC; c++) {
                s[c] += __shfl_xor(s[c], st, 64);
                q[c] += __shfl_xor(q[c], st, 64);
            }
        }
        int wid = threadIdx.x >> 6;
        int lane = threadIdx.x & 63;
        if (lane < 16) {
#pragma unroll
            for (int c = 0; c < VC; c++) { ps[wid][lane][c] = s[c]; pq[wid][lane][c] = q[c]; }
        }
        __syncthreads();
        if (threadIdx.x < DOUT) {
            int col = threadIdx.x;
            int cgi = col / VC, ci = col % VC;
            float t = ps[0][cgi][ci] + ps[1][cgi][ci] + ps[2][cgi][ci] + ps[3][cgi][ci];
            float t2 = pq[0][cgi][ci] + pq[1][cgi][ci] + pq[2][cgi][ci] + pq[3][cgi][ci];
            atomicAdd(&stats[col], (double)t);
            atomicAdd(&stats[DOUT + col], (double)t2);
        }
    }
}

// ---- stats sums -> per-channel scale/shift floats ----
template <int D>
__global__ void finalize_kernel(const double* __restrict__ stats,
                                const float* __restrict__ g, const float* __restrict__ be,
                                float* __restrict__ scale, float* __restrict__ shift, int n) {
    int c = threadIdx.x;
    if (c < D) {
        double mu = stats[c] / n;
        double var = stats[c + D] / n - mu * mu;
        double inv = 1.0 / sqrt(var + 1e-5);
        double sc = (double)g[c] * inv;
        scale[c] = (float)sc;
        shift[c] = (float)((double)be[c] - mu * sc);
    }
}

// ---- layer-3: BN normalize + GELU + residual(x) + mean-pool accumulate ----
__global__ __launch_bounds__(256) void norm_pool_kernel(const float* __restrict__ X3,
                                                        const float* __restrict__ x0,
                                                        const double* __restrict__ stats,
                                                        const float* __restrict__ gw,
                                                        const float* __restrict__ be,
                                                        double* __restrict__ pool, int n) {
    constexpr int D = 64;
    constexpr int RPB = 4;
    int c = threadIdx.x % D;
    double mu = stats[c] / n;
    double var = stats[c + D] / n - mu * mu;
    double inv = 1.0 / sqrt(var + 1e-5);
    float scale = (float)((double)gw[c] * inv);
    float shift = (float)((double)be[c] - mu * (double)gw[c] * inv);
    int r0 = threadIdx.x / D;
    int rowsPerGrid = gridDim.x * RPB;
    double s = 0.0;
    for (int r = blockIdx.x * RPB + r0; r < n; r += rowsPerGrid) {
        size_t idx = (size_t)r * D + c;
        float t = fmaf(X3[idx], scale, shift);
        float res = x0[idx] + gelu_f(t);
        s += res;
    }
    __shared__ double sh[256];
    sh[threadIdx.x] = s;
    __syncthreads();
    if (threadIdx.x < D) {
#pragma unroll
        for (int j = 1; j < RPB; j++) s += sh[threadIdx.x + j * D];
        atomicAdd(&pool[c], s);
    }
}

// ---- head MLP: 64 ->128 ->64 ->32 ->1, single block ----
__global__ __launch_bounds__(128) void mlp_kernel(const double* __restrict__ pool,
                                                  const float* __restrict__ w1, const float* __restrict__ b1,
                                                  const float* __restrict__ w2, const float* __restrict__ b2,
                                                  const float* __restrict__ w3, const float* __restrict__ b3,
                                                  const float* __restrict__ w4, const float* __restrict__ b4,
                                                  float* __restrict__ out, int n) {
    __shared__ float v0[64], h1[128], h2[64], h3[32];
    int t = threadIdx.x;
    if (t < 64) v0[t] = (float)(pool[t] / (double)n);
    __syncthreads();
    if (t < 128) {
        float a = b1[t];
        for (int k = 0; k < 64; k++) a = fmaf(v0[k], w1[k * 128 + t], a);
        h1[t] = gelu_f(a);
    }
    __syncthreads();
    if (t < 64) {
        float a = b2[t];
        for (int k = 0; k < 128; k++) a = fmaf(h1[k], w2[k * 64 + t], a);
        h2[t] = gelu_f(a);
    }
    __syncthreads();
    if (t < 32) {
        float a = b3[t];
        for (int k = 0; k < 64; k++) a = fmaf(h2[k], w3[k * 32 + t], a);
        h3[t] = gelu_f(a);
    }
    __syncthreads();
    if (t == 0) {
        float a = b4[0];
        for (int k = 0; k < 32; k++) a = fmaf(h3[k], w4[k], a);
        out[0] = a;
    }
}

extern "C" void kernel_launch(void* const* d_in, const int* in_sizes, int n_in,
                              void* d_out, int out_size, void* d_ws, size_t ws_size,
                              hipStream_t stream) {
    const float* x    = (const float*)d_in[0];
    const int*   ei   = (const int*)d_in[1];
    const float* W1   = (const float*)d_in[2];
    const float* b1   = (const float*)d_in[3];
    const float* g1   = (const float*)d_in[4];
    const float* be1  = (const float*)d_in[5];
    const float* W2   = (const float*)d_in[6];
    const float* b2   = (const float*)d_in[7];
    const float* g2   = (const float*)d_in[8];
    const float* be2  = (const float*)d_in[9];
    const float* W3   = (const float*)d_in[10];
    const float* b3   = (const float*)d_in[11];
    const float* g3   = (const float*)d_in[12];
    const float* be3  = (const float*)d_in[13];
    const float* fc1w = (const float*)d_in[14];
    const float* fc1b = (const float*)d_in[15];
    const float* fc2w = (const float*)d_in[16];
    const float* fc2b = (const float*)d_in[17];
    const float* fc3w = (const float*)d_in[18];
    const float* fc3b = (const float*)d_in[19];
    const float* fc4w = (const float*)d_in[20];
    const float* fc4b = (const float*)d_in[21];

    const int N = in_sizes[0] / 64;
    const int E = in_sizes[1] / 2;
    const int* e_row = ei;       // source
    const int* e_col = ei + E;   // target (aggregation index)

    // ---- workspace layout (~110 MB) ----
    char* ws = (char*)d_ws;
    size_t off = 0;
    double* stats1 = (double*)(ws + off); off += 256 * sizeof(double);
    double* stats2 = (double*)(ws + off); off += 256 * sizeof(double);
    double* stats3 = (double*)(ws + off); off += 256 * sizeof(double);
    double* pool   = (double*)(ws + off); off += 64 * sizeof(double);
    float* scale1 = (float*)(ws + off); off += 128 * sizeof(float);
    float* shift1 = (float*)(ws + off); off += 128 * sizeof(float);
    float* scale2 = (float*)(ws + off); off += 128 * sizeof(float);
    float* shift2 = (float*)(ws + off); off += 128 * sizeof(float);
    float* deg   = (float*)(ws + off); off += (size_t)N * sizeof(float);
    float* dinv  = (float*)(ws + off); off += (size_t)N * sizeof(float);
    off = (off + 15) & ~(size_t)15;
    int* offs    = (int*)(ws + off); off += (size_t)N * sizeof(int);
    int* cursor  = (int*)(ws + off); off += (size_t)N * sizeof(int);
    int* bsums   = (int*)(ws + off); off += 512 * sizeof(int);
    int* csr     = (int*)(ws + off); off += (size_t)E * sizeof(int);
    off = (off + 255) & ~(size_t)255;
    float* U     = (float*)(ws + off); off += (size_t)N * 128 * sizeof(float);  // gather table
    float* H     = (float*)(ws + off); off += (size_t)N * 128 * sizeof(float);  // row-major
    // alias: A1 = U head [N][64] (consumed by gemm1 before gemm2 overwrites U)
    float* A1 = U;

    const int nb256 = (N + 255) / 256;
    const int ebl = (E + 255) / 256;

    init_kernel<<<nb256, 256, 0, stream>>>(deg, stats1, N, 832);
    degree_kernel<<<ebl, 256, 0, stream>>>(e_col, deg, E);
    scan1_kernel<<<nb256, 256, 0, stream>>>(deg, dinv, offs, bsums, N);
    scan2_kernel<<<1, 512, 0, stream>>>(bsums, nb256);
    scan3_kernel<<<nb256, 256, 0, stream>>>(offs, bsums, cursor, N);
    fill_kernel<<<ebl, 256, 0, stream>>>(e_row, e_col, cursor, csr, E);

    // Layer 1: agg x in 64-dim (PRE) -> A1; GEMM(+b1,+stats1) -> H1
    agg_kernel<64, true, false, false><<<(N + 15) / 16, 256, 0, stream>>>(
        x, csr, offs, deg, dinv, nullptr, A1, nullptr, N);
    gemm_kernel<64, 128, false, true, false, true><<<(N + 63) / 64, 256, 0, stream>>>(
        A1, W1, nullptr, nullptr, b1, dinv, H, stats1, N);
    finalize_kernel<128><<<1, 128, 0, stream>>>(stats1, g1, be1, scale1, shift1, N);

    // Layer 2: GEMM (BN1+GELU fused, dinv prescale) -> U; agg(+b2,+stats2) -> H2
    gemm_kernel<128, 128, true, false, true, false><<<(N + 63) / 64, 256, 0, stream>>>(
        H, W2, scale1, shift1, nullptr, dinv, U, nullptr, N);
    agg_kernel<128, false, true, true><<<(N + 7) / 8, 256, 0, stream>>>(
        U, csr, offs, deg, dinv, b2, H, stats2, N);
    finalize_kernel<128><<<1, 128, 0, stream>>>(stats2, g2, be2, scale2, shift2, N);

    // Layer 3: GEMM (BN2+GELU fused, dinv prescale) 128->64 -> U; agg(+b3,+stats3) -> H3
    gemm_kernel<128, 64, true, false, true, false><<<(N + 63) / 64, 256, 0, stream>>>(
        H, W3, scale2, shift2, nullptr, dinv, U, nullptr, N);
    agg_kernel<64, false, true, true><<<(N + 15) / 16, 256, 0, stream>>>(
        U, csr, offs, deg, dinv, b3, H, stats3, N);

    // Epilogue: BN3+GELU+residual+meanpool, then head MLP
    norm_pool_kernel<<<1024, 256, 0, stream>>>(H, x, stats3, g3, be3, pool, N);
    mlp_kernel<<<1, 128, 0, stream>>>(pool, fc1w, fc1b, fc2w, fc2b, fc3w, fc3b,
                                      fc4w, fc4b, (float*)d_out, N);
}

// Round 9
// 668.223 us; speedup vs baseline: 2.3496x; 1.4136x over previous
//
#include <hip/hip_runtime.h>
#include <hip/hip_bf16.h>
#include <math.h>

// GNN: 3-layer GCN + BN + GELU + residual + meanpool + MLP -> scalar.
// R9: R2-exact gather loop (proven 3.65TB/s) + fused BN stats WITHOUT long
// atomic chains. R8 post-mortem: per-block double atomicAdds to 256 hot
// addresses serialize with chain depth = #blocks (12500x15ns ~= 187us tail,
// matches R4/R7/R8 measurements). Fix: 64-way spread tmp[(blk&63)][2D]
// (chain ~195 -> ~3us), folded by tiny 1-block combine/finalize kernels.

__device__ __forceinline__ float gelu_f(float x) {
    return 0.5f * x * (1.0f + erff(x * 0.7071067811865476f));
}

__device__ __forceinline__ int wave_incl_scan(int v, int lane) {
#pragma unroll
    for (int off = 1; off < 64; off <<= 1) {
        int t = __shfl_up(v, (unsigned)off, 64);
        if (lane >= off) v += t;
    }
    return v;
}

// ---- init: deg = 1.0 (self loop), zero double accumulators ----
__global__ void init_kernel(float* __restrict__ deg, double* __restrict__ dbls,
                            int n, int ndbl) {
    int i = blockIdx.x * 256 + threadIdx.x;
    if (i < n) deg[i] = 1.0f;
    if (i < ndbl) dbls[i] = 0.0;
}

__global__ void degree_kernel(const int* __restrict__ col, float* __restrict__ deg, int E) {
    int e = blockIdx.x * 256 + threadIdx.x;
    if (e < E) atomicAdd(&deg[col[e]], 1.0f);
}

__global__ __launch_bounds__(256) void scan1_kernel(const float* __restrict__ deg,
                                                    float* __restrict__ dinv,
                                                    int* __restrict__ offs,
                                                    int* __restrict__ bsums, int n) {
    int i = blockIdx.x * 256 + threadIdx.x;
    int lane = threadIdx.x & 63;
    int wid = threadIdx.x >> 6;
    int cnt = 0;
    if (i < n) {
        float d = deg[i];
        dinv[i] = 1.0f / sqrtf(d);
        cnt = (int)d - 1;
    }
    int incl = wave_incl_scan(cnt, lane);
    __shared__ int ws[4];
    if (lane == 63) ws[wid] = incl;
    __syncthreads();
    if (threadIdx.x == 0) {
        int a = 0;
#pragma unroll
        for (int j = 0; j < 4; j++) { int t = ws[j]; ws[j] = a; a += t; }
        bsums[blockIdx.x] = a;
    }
    __syncthreads();
    int excl = incl - cnt + ws[wid];
    if (i < n) offs[i] = excl;
}

__global__ __launch_bounds__(512) void scan2_kernel(int* __restrict__ bsums, int nblk) {
    int lane = threadIdx.x & 63;
    int wid = threadIdx.x >> 6;
    int v = (threadIdx.x < nblk) ? bsums[threadIdx.x] : 0;
    int incl = wave_incl_scan(v, lane);
    __shared__ int ws[8];
    if (lane == 63) ws[wid] = incl;
    __syncthreads();
    if (threadIdx.x == 0) {
        int a = 0;
#pragma unroll
        for (int j = 0; j < 8; j++) { int t = ws[j]; ws[j] = a; a += t; }
    }
    __syncthreads();
    int excl = incl - v + ws[wid];
    if (threadIdx.x < nblk) bsums[threadIdx.x] = excl;
}

__global__ void scan3_kernel(int* __restrict__ offs, const int* __restrict__ bsums,
                             int* __restrict__ cursor, int n) {
    int i = blockIdx.x * 256 + threadIdx.x;
    if (i < n) {
        int o = offs[i] + bsums[i >> 8];
        offs[i] = o;
        cursor[i] = o;
    }
}

__global__ void fill_kernel(const int* __restrict__ row, const int* __restrict__ col,
                            int* __restrict__ cursor, int* __restrict__ csr, int E) {
    int e = blockIdx.x * 256 + threadIdx.x;
    if (e < E) {
        int c = col[e];
        int pos = atomicAdd(&cursor[c], 1);
        csr[pos] = row[e];
    }
}

// ---- aggregation (R2-exact gather loop) + spread-atomic fused BN stats ----
// PRE=true : Out[i] = dinv_i * (dinv_i*U_i + sum_j dinv_j*U_j)         (no bias)
// PRE=false: Out[i] = dinv_i * (U_i + sum_j U_j) + bias                (U pre-scaled)
template <int D, bool PRE, bool STATS, bool BIAS>
__global__ __launch_bounds__(256) void agg_kernel(const float* __restrict__ U,
                                                  const int* __restrict__ csr,
                                                  const int* __restrict__ offs,
                                                  const float* __restrict__ deg,
                                                  const float* __restrict__ dinv,
                                                  const float* __restrict__ bias,
                                                  float* __restrict__ Out,
                                                  double* __restrict__ tmp, int n) {
    constexpr int GPN = D / 4;          // lanes per node (32 for D=128, 16 for D=64)
    constexpr int NPB = 256 / GPN;
    int g = threadIdx.x / GPN;
    int cl = threadIdx.x % GPN;
    int node = blockIdx.x * NPB + g;
    bool act = node < n;
    int c4 = cl * 4;

    float4 a0 = make_float4(0.f, 0.f, 0.f, 0.f), a1 = a0;
    int start = 0, cnt = 0;
    float dvi = 0.f;
    if (act) {
        start = offs[node];
        cnt = (int)deg[node] - 1;
        dvi = dinv[node];
        float4 self = *(const float4*)(U + (size_t)node * D + c4);
        if (PRE) {
            a0.x = self.x * dvi; a0.y = self.y * dvi;
            a0.z = self.z * dvi; a0.w = self.w * dvi;
        } else {
            a0 = self;
        }
    }
    int j = 0;
    for (; j + 4 <= cnt; j += 4) {
        int s0 = csr[start + j];
        int s1 = csr[start + j + 1];
        int s2 = csr[start + j + 2];
        int s3 = csr[start + j + 3];
        float4 v0 = *(const float4*)(U + (size_t)s0 * D + c4);
        float4 v1 = *(const float4*)(U + (size_t)s1 * D + c4);
        float4 v2 = *(const float4*)(U + (size_t)s2 * D + c4);
        float4 v3 = *(const float4*)(U + (size_t)s3 * D + c4);
        if (PRE) {
            float d0 = dinv[s0], d1 = dinv[s1], d2 = dinv[s2], d3 = dinv[s3];
            v0.x *= d0; v0.y *= d0; v0.z *= d0; v0.w *= d0;
            v1.x *= d1; v1.y *= d1; v1.z *= d1; v1.w *= d1;
            v2.x *= d2; v2.y *= d2; v2.z *= d2; v2.w *= d2;
            v3.x *= d3; v3.y *= d3; v3.z *= d3; v3.w *= d3;
        }
        a0.x += v0.x; a0.y += v0.y; a0.z += v0.z; a0.w += v0.w;
        a1.x += v1.x; a1.y += v1.y; a1.z += v1.z; a1.w += v1.w;
        a0.x += v2.x; a0.y += v2.y; a0.z += v2.z; a0.w += v2.w;
        a1.x += v3.x; a1.y += v3.y; a1.z += v3.z; a1.w += v3.w;
    }
    for (; j < cnt; j++) {
        int s = csr[start + j];
        float4 v = *(const float4*)(U + (size_t)s * D + c4);
        if (PRE) {
            float d = dinv[s];
            v.x *= d; v.y *= d; v.z *= d; v.w *= d;
        }
        a0.x += v.x; a0.y += v.y; a0.z += v.z; a0.w += v.w;
    }
    float4 acc;
    acc.x = a0.x + a1.x; acc.y = a0.y + a1.y;
    acc.z = a0.z + a1.z; acc.w = a0.w + a1.w;

    float h[4];
    h[0] = acc.x * dvi; h[1] = acc.y * dvi;
    h[2] = acc.z * dvi; h[3] = acc.w * dvi;
    if (BIAS) {
        float4 b4 = *(const float4*)(bias + c4);
        h[0] += b4.x; h[1] += b4.y; h[2] += b4.z; h[3] += b4.w;
    }
    if (act) {
        *(float4*)(Out + (size_t)node * D + c4) = make_float4(h[0], h[1], h[2], h[3]);
    } else {
        h[0] = h[1] = h[2] = h[3] = 0.f;   // no stats contribution
    }

    if (STATS) {
        float s[4], q[4];
#pragma unroll
        for (int c = 0; c < 4; c++) { s[c] = h[c]; q[c] = h[c] * h[c]; }
#pragma unroll
        for (int m = GPN; m < 64; m <<= 1) {
#pragma unroll
            for (int c = 0; c < 4; c++) {
                s[c] += __shfl_xor(s[c], m, 64);
                q[c] += __shfl_xor(q[c], m, 64);
            }
        }
        __shared__ float ps[4][GPN][4], pq[4][GPN][4];
        int wid = threadIdx.x >> 6;
        int lane = threadIdx.x & 63;
        if (lane < GPN) {
#pragma unroll
            for (int c = 0; c < 4; c++) { ps[wid][lane][c] = s[c]; pq[wid][lane][c] = q[c]; }
        }
        __syncthreads();
        if (threadIdx.x < D) {
            int cgi = threadIdx.x >> 2, ci = threadIdx.x & 3;
            float t1 = ps[0][cgi][ci] + ps[1][cgi][ci] + ps[2][cgi][ci] + ps[3][cgi][ci];
            float t2 = pq[0][cgi][ci] + pq[1][cgi][ci] + pq[2][cgi][ci] + pq[3][cgi][ci];
            int cp = (blockIdx.x & 63) * 2 * D;
            atomicAdd(&tmp[cp + threadIdx.x], (double)t1);
            atomicAdd(&tmp[cp + D + threadIdx.x], (double)t2);
        }
    }
}

// ---- register-blocked GEMM ----
// BNIN: scale/shift+GELU on input staging. STATS: spread-atomic sum/sumsq.
template <int DIN, int DOUT, bool BNIN, bool BIAS, bool DINVOUT, bool STATS>
__global__ __launch_bounds__(256) void gemm_kernel(const float* __restrict__ Hin,
                                                   const float* __restrict__ W,
                                                   const float* __restrict__ scale,
                                                   const float* __restrict__ shift,
                                                   const float* __restrict__ bias,
                                                   const float* __restrict__ dinv,
                                                   float* __restrict__ Out,
                                                   double* __restrict__ tmp, int n) {
    constexpr int BNODES = 64;
    constexpr int KT = 32;
    constexpr int HP = DIN + 4;
    constexpr int VC = DOUT / 16;      // 8 (DOUT=128) or 4 (DOUT=64)
    constexpr int C4 = VC / 4;
    __shared__ float Hs[BNODES * HP];
    __shared__ float Ws[KT * DOUT];
    __shared__ float ps[STATS ? 4 : 1][16][VC];
    __shared__ float pq[STATS ? 4 : 1][16][VC];

    int node0 = blockIdx.x * BNODES;
    int nv = n - node0;
    if (nv > BNODES) nv = BNODES;
    int cg = threadIdx.x & 15;
    int ng = threadIdx.x >> 4;

    constexpr int F4 = BNODES * (DIN / 4);
    for (int f = threadIdx.x; f < F4; f += 256) {
        int nn = f / (DIN / 4);
        int k4 = f - nn * (DIN / 4);
        float4 v = make_float4(0.f, 0.f, 0.f, 0.f);
        if (nn < nv)
            v = *(const float4*)(Hin + (size_t)(node0 + nn) * DIN + k4 * 4);
        if (BNIN) {
            float4 sc = *(const float4*)(scale + k4 * 4);
            float4 sh = *(const float4*)(shift + k4 * 4);
            v.x = gelu_f(fmaf(v.x, sc.x, sh.x));
            v.y = gelu_f(fmaf(v.y, sc.y, sh.y));
            v.z = gelu_f(fmaf(v.z, sc.z, sh.z));
            v.w = gelu_f(fmaf(v.w, sc.w, sh.w));
        }
        *(float4*)(Hs + nn * HP + k4 * 4) = v;
    }

    float acc[4][VC];
#pragma unroll
    for (int i = 0; i < 4; i++)
#pragma unroll
        for (int c = 0; c < VC; c++) acc[i][c] = 0.0f;

    for (int kb = 0; kb < DIN; kb += KT) {
        __syncthreads();
        for (int f = threadIdx.x; f < KT * DOUT / 4; f += 256)
            *(float4*)(Ws + f * 4) = *(const float4*)(W + (size_t)kb * DOUT + f * 4);
        __syncthreads();
#pragma unroll
        for (int kk = 0; kk < KT; kk++) {
            float h[4];
#pragma unroll
            for (int i = 0; i < 4; i++)
                h[i] = Hs[(ng * 4 + i) * HP + kb + kk];
            float w[VC];
#pragma unroll
            for (int c = 0; c < C4; c++) {
                float4 w4 = *(const float4*)(Ws + kk * DOUT + cg * VC + c * 4);
                w[c * 4 + 0] = w4.x; w[c * 4 + 1] = w4.y;
                w[c * 4 + 2] = w4.z; w[c * 4 + 3] = w4.w;
            }
#pragma unroll
            for (int i = 0; i < 4; i++)
#pragma unroll
                for (int c = 0; c < VC; c++)
                    acc[i][c] = fmaf(h[i], w[c], acc[i][c]);
        }
    }

    float fin[4][VC];
#pragma unroll
    for (int i = 0; i < 4; i++) {
        int nn = ng * 4 + i;
        bool valid = nn < nv;
        int node = node0 + nn;
        float dv = 1.0f;
        if (DINVOUT && valid) dv = dinv[node];
#pragma unroll
        for (int c = 0; c < VC; c++) {
            float f = acc[i][c] * dv;
            if (BIAS) f += bias[cg * VC + c];
            fin[i][c] = valid ? f : 0.f;
        }
        if (valid) {
#pragma unroll
            for (int c = 0; c < C4; c++)
                *(float4*)(Out + (size_t)node * DOUT + cg * VC + c * 4) =
                    make_float4(fin[i][c * 4 + 0], fin[i][c * 4 + 1],
                                fin[i][c * 4 + 2], fin[i][c * 4 + 3]);
        }
    }

    if (STATS) {
        float s[VC], q[VC];
#pragma unroll
        for (int c = 0; c < VC; c++) {
            s[c] = fin[0][c] + fin[1][c] + fin[2][c] + fin[3][c];
            q[c] = fin[0][c] * fin[0][c] + fin[1][c] * fin[1][c] +
                   fin[2][c] * fin[2][c] + fin[3][c] * fin[3][c];
        }
#pragma unroll
        for (int st = 16; st < 64; st <<= 1) {
#pragma unroll
            for (int c = 0; c < VC; c++) {
                s[c] += __shfl_xor(s[c], st, 64);
                q[c] += __shfl_xor(q[c], st, 64);
            }
        }
        int wid = threadIdx.x >> 6;
        int lane = threadIdx.x & 63;
        if (lane < 16) {
#pragma unroll
            for (int c = 0; c < VC; c++) { ps[wid][lane][c] = s[c]; pq[wid][lane][c] = q[c]; }
        }
        __syncthreads();
        if (threadIdx.x < DOUT) {
            int col = threadIdx.x;
            int cgi = col / VC, ci = col % VC;
            float t = ps[0][cgi][ci] + ps[1][cgi][ci] + ps[2][cgi][ci] + ps[3][cgi][ci];
            float t2 = pq[0][cgi][ci] + pq[1][cgi][ci] + pq[2][cgi][ci] + pq[3][cgi][ci];
            int cp = (blockIdx.x & 63) * 2 * DOUT;
            atomicAdd(&tmp[cp + col], (double)t);
            atomicAdd(&tmp[cp + DOUT + col], (double)t2);
        }
    }
}

// ---- fold 64 tmp copies -> per-channel scale/shift floats ----
template <int D>
__global__ void finalize_tmp_kernel(const double* __restrict__ tmp,
                                    const float* __restrict__ g, const float* __restrict__ be,
                                    float* __restrict__ scale, float* __restrict__ shift, int n) {
    int c = threadIdx.x;
    if (c < D) {
        double s = 0.0, q = 0.0;
        for (int gg = 0; gg < 64; gg++) {
            s += tmp[gg * 2 * D + c];
            q += tmp[gg * 2 * D + D + c];
        }
        double mu = s / n;
        double var = q / n - mu * mu;
        double inv = 1.0 / sqrt(var + 1e-5);
        double sc = (double)g[c] * inv;
        scale[c] = (float)sc;
        shift[c] = (float)((double)be[c] - mu * sc);
    }
}

// ---- fold 64 tmp copies -> raw stats sums (for norm_pool) ----
template <int D>
__global__ void combine_kernel(const double* __restrict__ tmp, double* __restrict__ stats) {
    int t = threadIdx.x;
    if (t < 2 * D) {
        double s = 0.0;
        for (int gg = 0; gg < 64; gg++) s += tmp[gg * 2 * D + t];
        stats[t] = s;
    }
}

// ---- layer-3: BN normalize + GELU + residual(x) + mean-pool accumulate ----
__global__ __launch_bounds__(256) void norm_pool_kernel(const float* __restrict__ X3,
                                                        const float* __restrict__ x0,
                                                        const double* __restrict__ stats,
                                                        const float* __restrict__ gw,
                                                        const float* __restrict__ be,
                                                        double* __restrict__ pool, int n) {
    constexpr int D = 64;
    constexpr int RPB = 4;
    int c = threadIdx.x % D;
    double mu = stats[c] / n;
    double var = stats[c + D] / n - mu * mu;
    double inv = 1.0 / sqrt(var + 1e-5);
    float scale = (float)((double)gw[c] * inv);
    float shift = (float)((double)be[c] - mu * (double)gw[c] * inv);
    int r0 = threadIdx.x / D;
    int rowsPerGrid = gridDim.x * RPB;
    double s = 0.0;
    for (int r = blockIdx.x * RPB + r0; r < n; r += rowsPerGrid) {
        size_t idx = (size_t)r * D + c;
        float t = fmaf(X3[idx], scale, shift);
        float res = x0[idx] + gelu_f(t);
        s += res;
    }
    __shared__ double sh[256];
    sh[threadIdx.x] = s;
    __syncthreads();
    if (threadIdx.x < D) {
#pragma unroll
        for (int j = 1; j < RPB; j++) s += sh[threadIdx.x + j * D];
        atomicAdd(&pool[c], s);
    }
}

// ---- head MLP: 64 ->128 ->64 ->32 ->1, single block ----
__global__ __launch_bounds__(128) void mlp_kernel(const double* __restrict__ pool,
                                                  const float* __restrict__ w1, const float* __restrict__ b1,
                                                  const float* __restrict__ w2, const float* __restrict__ b2,
                                                  const float* __restrict__ w3, const float* __restrict__ b3,
                                                  const float* __restrict__ w4, const float* __restrict__ b4,
                                                  float* __restrict__ out, int n) {
    __shared__ float v0[64], h1[128], h2[64], h3[32];
    int t = threadIdx.x;
    if (t < 64) v0[t] = (float)(pool[t] / (double)n);
    __syncthreads();
    if (t < 128) {
        float a = b1[t];
        for (int k = 0; k < 64; k++) a = fmaf(v0[k], w1[k * 128 + t], a);
        h1[t] = gelu_f(a);
    }
    __syncthreads();
    if (t < 64) {
        float a = b2[t];
        for (int k = 0; k < 128; k++) a = fmaf(h1[k], w2[k * 64 + t], a);
        h2[t] = gelu_f(a);
    }
    __syncthreads();
    if (t < 32) {
        float a = b3[t];
        for (int k = 0; k < 64; k++) a = fmaf(h2[k], w3[k * 32 + t], a);
        h3[t] = gelu_f(a);
    }
    __syncthreads();
    if (t == 0) {
        float a = b4[0];
        for (int k = 0; k < 32; k++) a = fmaf(h3[k], w4[k], a);
        out[0] = a;
    }
}

extern "C" void kernel_launch(void* const* d_in, const int* in_sizes, int n_in,
                              void* d_out, int out_size, void* d_ws, size_t ws_size,
                              hipStream_t stream) {
    const float* x    = (const float*)d_in[0];
    const int*   ei   = (const int*)d_in[1];
    const float* W1   = (const float*)d_in[2];
    const float* b1   = (const float*)d_in[3];
    const float* g1   = (const float*)d_in[4];
    const float* be1  = (const float*)d_in[5];
    const float* W2   = (const float*)d_in[6];
    const float* b2   = (const float*)d_in[7];
    const float* g2   = (const float*)d_in[8];
    const float* be2  = (const float*)d_in[9];
    const float* W3   = (const float*)d_in[10];
    const float* b3   = (const float*)d_in[11];
    const float* g3   = (const float*)d_in[12];
    const float* be3  = (const float*)d_in[13];
    const float* fc1w = (const float*)d_in[14];
    const float* fc1b = (const float*)d_in[15];
    const float* fc2w = (const float*)d_in[16];
    const float* fc2b = (const float*)d_in[17];
    const float* fc3w = (const float*)d_in[18];
    const float* fc3b = (const float*)d_in[19];
    const float* fc4w = (const float*)d_in[20];
    const float* fc4b = (const float*)d_in[21];

    const int N = in_sizes[0] / 64;
    const int E = in_sizes[1] / 2;
    const int* e_row = ei;       // source
    const int* e_col = ei + E;   // target (aggregation index)

    // ---- workspace layout (~111 MB) ----
    char* ws = (char*)d_ws;
    size_t off = 0;
    double* pool   = (double*)(ws + off); off += 64 * sizeof(double);
    double* tmp1   = (double*)(ws + off); off += 64 * 256 * sizeof(double);  // gemm1 stats spread
    double* tmp2   = (double*)(ws + off); off += 64 * 256 * sizeof(double);  // agg2 stats spread
    double* tmp3   = (double*)(ws + off); off += 64 * 128 * sizeof(double);  // agg3 stats spread
    double* stats3 = (double*)(ws + off); off += 128 * sizeof(double);
    const int NDBL = 64 + 64 * 256 * 2 + 64 * 128 + 128;  // zeroed by init
    float* scale1 = (float*)(ws + off); off += 128 * sizeof(float);
    float* shift1 = (float*)(ws + off); off += 128 * sizeof(float);
    float* scale2 = (float*)(ws + off); off += 128 * sizeof(float);
    float* shift2 = (float*)(ws + off); off += 128 * sizeof(float);
    float* deg   = (float*)(ws + off); off += (size_t)N * sizeof(float);
    float* dinv  = (float*)(ws + off); off += (size_t)N * sizeof(float);
    off = (off + 15) & ~(size_t)15;
    int* offs    = (int*)(ws + off); off += (size_t)N * sizeof(int);
    int* cursor  = (int*)(ws + off); off += (size_t)N * sizeof(int);
    int* bsums   = (int*)(ws + off); off += 512 * sizeof(int);
    int* csr     = (int*)(ws + off); off += (size_t)E * sizeof(int);
    off = (off + 255) & ~(size_t)255;
    float* U     = (float*)(ws + off); off += (size_t)N * 128 * sizeof(float);  // gather table
    float* H     = (float*)(ws + off); off += (size_t)N * 128 * sizeof(float);  // row-major
    // alias: A1 = U head [N][64] (consumed by gemm1 before gemm2 overwrites U)
    float* A1 = U;

    const int nb256 = (N + 255) / 256;
    const int ebl = (E + 255) / 256;

    init_kernel<<<nb256, 256, 0, stream>>>(deg, pool, N, NDBL);
    degree_kernel<<<ebl, 256, 0, stream>>>(e_col, deg, E);
    scan1_kernel<<<nb256, 256, 0, stream>>>(deg, dinv, offs, bsums, N);
    scan2_kernel<<<1, 512, 0, stream>>>(bsums, nb256);
    scan3_kernel<<<nb256, 256, 0, stream>>>(offs, bsums, cursor, N);
    fill_kernel<<<ebl, 256, 0, stream>>>(e_row, e_col, cursor, csr, E);

    // Layer 1: agg x in 64-dim (PRE) -> A1; GEMM(+b1,+stats->tmp1) -> H1
    agg_kernel<64, true, false, false><<<(N + 15) / 16, 256, 0, stream>>>(
        x, csr, offs, deg, dinv, nullptr, A1, nullptr, N);
    gemm_kernel<64, 128, false, true, false, true><<<(N + 63) / 64, 256, 0, stream>>>(
        A1, W1, nullptr, nullptr, b1, dinv, H, tmp1, N);
    finalize_tmp_kernel<128><<<1, 128, 0, stream>>>(tmp1, g1, be1, scale1, shift1, N);

    // Layer 2: GEMM (BN1+GELU fused, dinv prescale) -> U; agg(+b2,+stats->tmp2) -> H2
    gemm_kernel<128, 128, true, false, true, false><<<(N + 63) / 64, 256, 0, stream>>>(
        H, W2, scale1, shift1, nullptr, dinv, U, nullptr, N);
    agg_kernel<128, false, true, true><<<(N + 7) / 8, 256, 0, stream>>>(
        U, csr, offs, deg, dinv, b2, H, tmp2, N);
    finalize_tmp_kernel<128><<<1, 128, 0, stream>>>(tmp2, g2, be2, scale2, shift2, N);

    // Layer 3: GEMM (BN2+GELU fused, dinv prescale) 128->64 -> U; agg(+b3,+stats->tmp3) -> H3
    gemm_kernel<128, 64, true, false, true, false><<<(N + 63) / 64, 256, 0, stream>>>(
        H, W3, scale2, shift2, nullptr, dinv, U, nullptr, N);
    agg_kernel<64, false, true, true><<<(N + 15) / 16, 256, 0, stream>>>(
        U, csr, offs, deg, dinv, b3, H, tmp3, N);
    combine_kernel<64><<<1, 128, 0, stream>>>(tmp3, stats3);

    // Epilogue: BN3+GELU+residual+meanpool, then head MLP
    norm_pool_kernel<<<1024, 256, 0, stream>>>(H, x, stats3, g3, be3, pool, N);
    mlp_kernel<<<1, 128, 0, stream>>>(pool, fc1w, fc1b, fc2w, fc2b, fc3w, fc3b,
                                      fc4w, fc4b, (float*)d_out, N);
}